// Round 3
// baseline (4559.664 us; speedup 1.0000x reference)
//
#include <hip/hip_runtime.h>
#include <hip/hip_bf16.h>
#include <stdint.h>

typedef float  f32x4  __attribute__((ext_vector_type(4)));
typedef __bf16 bf16x8 __attribute__((ext_vector_type(8)));
typedef unsigned short u16x8 __attribute__((ext_vector_type(8)));

__device__ __forceinline__ unsigned short f2bf_rne(float f) {
    uint32_t x = __float_as_uint(f);
    uint32_t r = x + 0x7FFFu + ((x >> 16) & 1u);
    return (unsigned short)(r >> 16);
}

__global__ __launch_bounds__(256) void cvt_f32_bf16(const float* __restrict__ src,
                                                    unsigned short* __restrict__ dst,
                                                    long n) {
    long i0 = ((long)blockIdx.x * blockDim.x + threadIdx.x) * 8;
    long stride = (long)gridDim.x * blockDim.x * 8;
    for (long j = i0; j + 8 <= n; j += stride) {
        float4 v0 = *(const float4*)(src + j);
        float4 v1 = *(const float4*)(src + j + 4);
        u16x8 o;
        o[0] = f2bf_rne(v0.x); o[1] = f2bf_rne(v0.y);
        o[2] = f2bf_rne(v0.z); o[3] = f2bf_rne(v0.w);
        o[4] = f2bf_rne(v1.x); o[5] = f2bf_rne(v1.y);
        o[6] = f2bf_rne(v1.z); o[7] = f2bf_rne(v1.w);
        *(u16x8*)(dst + j) = o;
    }
}

#define GLL(SRC, DST) __builtin_amdgcn_global_load_lds(                      \
    (const __attribute__((address_space(1))) void*)(SRC),                    \
    (__attribute__((address_space(3))) void*)(DST), 16, 0, 0)
#define BARRIER() asm volatile("s_barrier" ::: "memory")
#define WAITV(N) asm volatile("s_waitcnt vmcnt(" #N ")" ::: "memory")
#define WAITL(N) do { asm volatile("s_waitcnt lgkmcnt(" #N ")" ::: "memory"); \
                      __builtin_amdgcn_sched_barrier(0); } while (0)

// 256x256 tile, BK=64, 8 waves (2M x 4N), double-buffered 128 KiB LDS.
// 8 phases per 2 K-tiles; ds_reads issued ONE PHASE AHEAD into ping-pong
// register sets; pre-MFMA gate is a counted lgkmcnt (not 0). vmcnt(6)@P4 /
// vmcnt(4)@P8. Peeled tail iteration with vmcnt(0).
__global__ __launch_bounds__(512, 2) void gemm256_8p(
    const unsigned short* __restrict__ A, const unsigned short* __restrict__ B,
    const float* __restrict__ bias, float* __restrict__ C,
    int M, int N, int K) {
    __shared__ __align__(16) char lds[131072];
    const int tid  = threadIdx.x;
    const int lane = tid & 63;
    const int wave = tid >> 6;
    const int wr  = wave >> 2;   // 0..1
    const int wc  = wave & 3;    // 0..3
    const int l15 = lane & 15;
    const int l4  = lane >> 4;

    // bijective XCD swizzle
    int bid = blockIdx.x, nwg = gridDim.x;
    int qq = nwg >> 3, rr = nwg & 7, xc = bid & 7, oo = bid >> 3;
    int wg = (xc < rr ? xc * (qq + 1) : rr * (qq + 1) + (xc - rr) * qq) + oo;
    const int nTn = N >> 8;
    const long m0 = (long)(wg / nTn) << 8;
    const long n0 = (long)(wg % nTn) << 8;

    const int colSw = ((tid & 7) ^ ((tid >> 3) & 7)) << 3;
    const int aRow  = tid >> 3;
    const int bWcLo = tid >> 8;
    const int bR    = (tid >> 3) & 31;
    const long Kl = K;

    auto STAGE_A = [&](int buf, int u, int t) {
        char* dst = lds + (buf << 16) + (u << 14) + tid * 16;
        long col = (long)t * 64 + colSw;
#pragma unroll
        for (int i = 0; i < 2; ++i) {
            const unsigned short* src = A + (m0 + i * 128 + u * 64 + aRow) * Kl + col;
            GLL(src, dst + i * 8192);
        }
    };
    auto STAGE_B = [&](int buf, int u, int t) {
        char* dst = lds + (buf << 16) + 32768 + (u << 14) + tid * 16;
        long col = (long)t * 64 + colSw;
#pragma unroll
        for (int i = 0; i < 2; ++i) {
            const unsigned short* src = B + (n0 + (i * 2 + bWcLo) * 64 + u * 32 + bR) * Kl + col;
            GLL(src, dst + i * 8192);
        }
    };
    auto LDA = [&](int buf, int mh, int m, int kk) -> bf16x8 {
        int off = (((m * 16 + l15) * 64 + kk * 32 + l4 * 8) * 2) ^ ((l15 & 7) << 4);
        return *(const bf16x8*)(lds + (buf << 16) + (mh << 14) + (wr << 13) + off);
    };
    auto LDB = [&](int buf, int nh, int n, int kk) -> bf16x8 {
        int off = (((n * 16 + l15) * 64 + kk * 32 + l4 * 8) * 2) ^ ((l15 & 7) << 4);
        return *(const bf16x8*)(lds + (buf << 16) + 32768 + (nh << 14) + (wc << 12) + off);
    };

    f32x4 acc[8][4] = {};
    bf16x8 afA[4][2], afB[4][2], afA2[4][2], afB2[4][2];
    bf16x8 bqA[2][2], bqB[2][2], bqA2[2][2], bqB2[2][2];

    auto RD_A = [&](bf16x8 (&d)[4][2], int buf, int mh) {
#pragma unroll
        for (int m = 0; m < 4; ++m) { d[m][0] = LDA(buf, mh, m, 0); d[m][1] = LDA(buf, mh, m, 1); }
    };
    auto RD_B = [&](bf16x8 (&d)[2][2], int buf, int nh) {
#pragma unroll
        for (int n = 0; n < 2; ++n) { d[n][0] = LDB(buf, nh, n, 0); d[n][1] = LDB(buf, nh, n, 1); }
    };
    auto MFMA_Q = [&](bf16x8 (&af)[4][2], bf16x8 (&bq)[2][2], int mo, int no) {
        __builtin_amdgcn_s_setprio(1);
#pragma unroll
        for (int kk = 0; kk < 2; ++kk)
#pragma unroll
            for (int m = 0; m < 4; ++m)
#pragma unroll
                for (int n = 0; n < 2; ++n)
                    acc[mo + m][no + n] = __builtin_amdgcn_mfma_f32_16x16x32_bf16(
                        af[m][kk], bq[n][kk], acc[mo + m][no + n], 0, 0, 0);
        __builtin_amdgcn_s_setprio(0);
    };

    const int NT = K >> 6;

    // prologue: stage tiles 0 (buf0) and 1 (buf1); leave last 4 loads (B1o,A1o) in flight
    STAGE_A(0, 0, 0); STAGE_B(0, 0, 0); STAGE_B(0, 1, 0); STAGE_A(0, 1, 0);
    STAGE_A(1, 0, 1); STAGE_B(1, 0, 1); STAGE_B(1, 1, 1); STAGE_A(1, 1, 1);
    WAITV(4);
    BARRIER();
    RD_A(afA, 0, 0);   // A0 @ tile0
    RD_B(bqA, 0, 0);   // B0 @ tile0

    for (int t = 0; t + 3 < NT; t += 2) {
        // P1: Q00(e) = afA x bqA ; prefetch bqB(B1@e) ; stage A0e,B0e(t+2)
        RD_B(bqB, 0, 1);
        STAGE_A(0, 0, t + 2); STAGE_B(0, 0, t + 2);
        BARRIER(); WAITL(4);
        MFMA_Q(afA, bqA, 0, 0);
        BARRIER();
        // P2: Q01(e) = afA x bqB ; prefetch afB(A1@e) ; stage B1e(t+2)
        RD_A(afB, 0, 1);
        STAGE_B(0, 1, t + 2);
        BARRIER(); WAITL(8);
        MFMA_Q(afA, bqB, 0, 2);
        BARRIER();
        // P3: Q11(e) = afB x bqB ; prefetch afA2(A0@o) ; stage A1e(t+2)
        RD_A(afA2, 1, 0);
        STAGE_A(0, 1, t + 2);
        BARRIER(); WAITL(8);
        MFMA_Q(afB, bqB, 4, 2);
        BARRIER();
        // P4: Q10(e) = afB x bqA ; prefetch bqA2(B0@o) ; stage A0o(t+3) ; vmcnt(6)
        RD_B(bqA2, 1, 0);
        STAGE_A(1, 0, t + 3);
        WAITV(6);
        BARRIER(); WAITL(12);
        MFMA_Q(afB, bqA, 4, 0);
        BARRIER();
        // P5: Q00(o) = afA2 x bqA2 ; prefetch bqB2(B1@o) ; stage B0o(t+3)
        RD_B(bqB2, 1, 1);
        STAGE_B(1, 0, t + 3);
        BARRIER(); WAITL(4);
        MFMA_Q(afA2, bqA2, 0, 0);
        BARRIER();
        // P6: Q01(o) = afA2 x bqB2 ; prefetch afB2(A1@o) ; stage B1o(t+3)
        RD_A(afB2, 1, 1);
        STAGE_B(1, 1, t + 3);
        BARRIER(); WAITL(8);
        MFMA_Q(afA2, bqB2, 0, 2);
        BARRIER();
        // P7: Q11(o) = afB2 x bqB2 ; prefetch afA(A0@e, t+2) ; stage A1o(t+3)
        RD_A(afA, 0, 0);
        STAGE_A(1, 1, t + 3);
        BARRIER(); WAITL(8);
        MFMA_Q(afB2, bqB2, 4, 2);
        BARRIER();
        // P8: Q10(o) = afB2 x bqA2 ; prefetch bqA(B0@e, t+2) ; vmcnt(4)
        RD_B(bqA, 0, 0);
        WAITV(4);
        BARRIER(); WAITL(12);
        MFMA_Q(afB2, bqA2, 4, 0);
        BARRIER();
    }

    // tail: tiles NT-2 (buf0), NT-1 (buf1) — no stages, no cross-iter prefetch
    {
        RD_B(bqB, 0, 1);
        BARRIER(); WAITL(4);
        MFMA_Q(afA, bqA, 0, 0);
        BARRIER();
        RD_A(afB, 0, 1);
        BARRIER(); WAITL(8);
        MFMA_Q(afA, bqB, 0, 2);
        BARRIER();
        RD_A(afA2, 1, 0);
        BARRIER(); WAITL(8);
        MFMA_Q(afB, bqB, 4, 2);
        BARRIER();
        RD_B(bqA2, 1, 0);
        WAITV(0);
        BARRIER(); WAITL(12);
        MFMA_Q(afB, bqA, 4, 0);
        BARRIER();
        RD_B(bqB2, 1, 1);
        BARRIER(); WAITL(4);
        MFMA_Q(afA2, bqA2, 0, 0);
        BARRIER();
        RD_A(afB2, 1, 1);
        BARRIER(); WAITL(8);
        MFMA_Q(afA2, bqB2, 0, 2);
        BARRIER();
        BARRIER(); WAITL(0);
        MFMA_Q(afB2, bqB2, 4, 2);
        BARRIER();
        BARRIER(); WAITL(0);
        MFMA_Q(afB2, bqA2, 4, 0);
        BARRIER();
    }

    // epilogue: D mapping col = l15, row = l4*4 + j within each 16x16 fragment
#pragma unroll
    for (int nf = 0; nf < 4; ++nf) {
        const long col = n0 + wc * 64 + nf * 16 + l15;
        const float bv = bias[col];
#pragma unroll
        for (int mf = 0; mf < 8; ++mf) {
            float* Cp = C + (m0 + wr * 128 + mf * 16 + l4 * 4) * (long)N + col;
#pragma unroll
            for (int j = 0; j < 4; ++j)
                Cp[(long)j * N] = acc[mf][nf][j] + bv;
        }
    }
}

// fallback: m97-structure 128x128 (verified round 1)
__global__ __launch_bounds__(256) void gemm_bt_bias(const unsigned short* __restrict__ A,
                                                    const unsigned short* __restrict__ B,
                                                    const float* __restrict__ bias,
                                                    float* __restrict__ C,
                                                    int M, int N, int K) {
    __shared__ unsigned short lds_a[128 * 32];
    __shared__ unsigned short lds_b[128 * 32];
    const int tid  = threadIdx.x;
    const int lane = tid & 63;
    const int wave = tid >> 6;
    const int wrr = wave >> 1, wcc = wave & 1;
    const int l15 = lane & 15, l4 = lane >> 4;
    const int nTilesN = N / 128;
    const long m0 = (long)(blockIdx.x / nTilesN) * 128;
    const long n0 = (long)(blockIdx.x % nTilesN) * 128;
    f32x4 acc[4][4] = {};
    const unsigned short* aSrc = A + (m0 + (tid >> 2)) * (long)K + ((tid & 3) * 8);
    const unsigned short* bSrc = B + (n0 + (tid >> 2)) * (long)K + ((tid & 3) * 8);
    char* aDst = (char*)lds_a + tid * 16;
    char* bDst = (char*)lds_b + tid * 16;
    for (int k0 = 0; k0 < K; k0 += 32) {
#pragma unroll
        for (int i = 0; i < 2; i++) {
            GLL(aSrc + (long)i * 64 * K + k0, aDst + i * 4096);
            GLL(bSrc + (long)i * 64 * K + k0, bDst + i * 4096);
        }
        __syncthreads();
        bf16x8 afr[4], bfr[4];
#pragma unroll
        for (int r = 0; r < 4; r++)
            afr[r] = *(const bf16x8*)&lds_a[(wrr * 64 + r * 16 + l15) * 32 + l4 * 8];
#pragma unroll
        for (int c = 0; c < 4; c++)
            bfr[c] = *(const bf16x8*)&lds_b[(wcc * 64 + c * 16 + l15) * 32 + l4 * 8];
#pragma unroll
        for (int r = 0; r < 4; r++)
#pragma unroll
            for (int c = 0; c < 4; c++)
                acc[r][c] = __builtin_amdgcn_mfma_f32_16x16x32_bf16(afr[r], bfr[c], acc[r][c], 0, 0, 0);
        __syncthreads();
    }
#pragma unroll
    for (int c = 0; c < 4; c++) {
        const long n = n0 + wcc * 64 + c * 16 + l15;
        const float bv = bias[n];
#pragma unroll
        for (int r = 0; r < 4; r++) {
            const long m = m0 + wrr * 64 + r * 16 + l4 * 4;
            float* Cp = C + m * (long)N + n;
#pragma unroll
            for (int j = 0; j < 4; j++)
                Cp[(long)j * N] = acc[r][c][j] + bv;
        }
    }
}

extern "C" void kernel_launch(void* const* d_in, const int* in_sizes, int n_in,
                              void* d_out, int out_size, void* d_ws, size_t ws_size,
                              hipStream_t stream) {
    const float* x    = (const float*)d_in[0];
    const float* w    = (const float*)d_in[1];
    const float* bias = (const float*)d_in[2];
    float* out = (float*)d_out;

    const long Nn = in_sizes[2];             // OUT = 4096
    const long Kk = (long)in_sizes[1] / Nn;  // IN  = 16384
    const long Mm = (long)in_sizes[0] / Kk;  // B*S = 8192

    unsigned short* aB = (unsigned short*)d_ws;
    unsigned short* bB = aB + Mm * Kk;
    cvt_f32_bf16<<<2048, 256, 0, stream>>>(x, aB, Mm * Kk);
    cvt_f32_bf16<<<2048, 256, 0, stream>>>(w, bB, Nn * Kk);

    if ((Mm & 255) == 0 && (Nn & 255) == 0 && (Kk & 127) == 0 && Kk >= 256) {
        const int grid = (int)((Mm >> 8) * (Nn >> 8));
        gemm256_8p<<<grid, 512, 0, stream>>>(aB, bB, bias, out, (int)Mm, (int)Nn, (int)Kk);
    } else {
        const int grid = (int)((Mm / 128) * (Nn / 128));
        gemm_bt_bias<<<grid, 256, 0, stream>>>(aB, bB, bias, out, (int)Mm, (int)Nn, (int)Kk);
    }
}

// Round 4
// 1334.583 us; speedup vs baseline: 3.4165x; 3.4165x over previous
//
#include <hip/hip_runtime.h>
#include <hip/hip_bf16.h>
#include <stdint.h>

typedef float  f32x4  __attribute__((ext_vector_type(4)));
typedef float  f32x16 __attribute__((ext_vector_type(16)));
typedef __bf16 bf16x8 __attribute__((ext_vector_type(8)));
typedef unsigned short u16x8 __attribute__((ext_vector_type(8)));

__device__ __forceinline__ unsigned short f2bf_rne(float f) {
    uint32_t x = __float_as_uint(f);
    uint32_t r = x + 0x7FFFu + ((x >> 16) & 1u);
    return (unsigned short)(r >> 16);
}

__global__ __launch_bounds__(256) void cvt_f32_bf16(const float* __restrict__ src,
                                                    unsigned short* __restrict__ dst,
                                                    long n) {
    long i0 = ((long)blockIdx.x * blockDim.x + threadIdx.x) * 8;
    long stride = (long)gridDim.x * blockDim.x * 8;
    for (long j = i0; j + 8 <= n; j += stride) {
        float4 v0 = *(const float4*)(src + j);
        float4 v1 = *(const float4*)(src + j + 4);
        u16x8 o;
        o[0] = f2bf_rne(v0.x); o[1] = f2bf_rne(v0.y);
        o[2] = f2bf_rne(v0.z); o[3] = f2bf_rne(v0.w);
        o[4] = f2bf_rne(v1.x); o[5] = f2bf_rne(v1.y);
        o[6] = f2bf_rne(v1.z); o[7] = f2bf_rne(v1.w);
        *(u16x8*)(dst + j) = o;
    }
}

#define GLL(SRC, DST) __builtin_amdgcn_global_load_lds(                      \
    (const __attribute__((address_space(1))) void*)(SRC),                    \
    (__attribute__((address_space(3))) void*)(DST), 16, 0, 0)
#define BARRIER() asm volatile("s_barrier" ::: "memory")
#define WAITV(N) asm volatile("s_waitcnt vmcnt(" #N ")" ::: "memory")
#define WAITL(N) do { asm volatile("s_waitcnt lgkmcnt(" #N ")" ::: "memory"); \
                      __builtin_amdgcn_sched_barrier(0); } while (0)

// 256x256 tile, BK=64, 8 waves (2M x 4N), 128 KiB double-buffered LDS.
// 32x32x16 MFMA. 2 phases/tile; A-fragments prefetched ONE PHASE AHEAD
// (2 register sets), MFMA gated by counted lgkmcnt(8). All 8 GLLs for
// tile t+2 issued at phase-1-post; single vmcnt(0) visibility gate at
// phase-1-pre (full-tile in-flight window > HBM latency).
__global__ __launch_bounds__(512, 2) void gemm256_32x32(
    const unsigned short* __restrict__ A, const unsigned short* __restrict__ B,
    const float* __restrict__ bias, float* __restrict__ C,
    int M, int N, int K) {
    __shared__ __align__(16) char lds[131072];
    const int tid  = threadIdx.x;
    const int lane = tid & 63;
    const int wave = tid >> 6;
    const int wr  = wave >> 2;   // 0..1
    const int wc  = wave & 3;    // 0..3
    const int l31 = lane & 31;
    const int l5  = lane >> 5;   // 0..1

    // bijective XCD swizzle
    int bid = blockIdx.x, nwg = gridDim.x;
    int qq = nwg >> 3, rr = nwg & 7, xc = bid & 7, oo = bid >> 3;
    int wg = (xc < rr ? xc * (qq + 1) : rr * (qq + 1) + (xc - rr) * qq) + oo;
    const int nTn = N >> 8;
    const long m0 = (long)(wg / nTn) << 8;
    const long n0 = (long)(wg % nTn) << 8;

    const int colSw = ((tid & 7) ^ ((tid >> 3) & 7)) << 3;  // inverse-swizzled k-block
    const int aRow  = tid >> 3;
    const int bWcLo = tid >> 8;
    const int bR    = (tid >> 3) & 31;
    const long Kl = K;

    // identical staging layout to round 2 (verified):
    // A buf: unit u (16 KiB) = rows [u*64,u*64+64) (i=0) + [128+u*64,...) (i=1)
    // B buf: unit u at 32768 + u*16384, sub-blocks of 32 rows x 128 B
    auto STAGE_A = [&](int buf, int u, int t) {
        char* dst = lds + (buf << 16) + (u << 14) + tid * 16;
        long col = (long)t * 64 + colSw;
#pragma unroll
        for (int i = 0; i < 2; ++i) {
            const unsigned short* src = A + (m0 + i * 128 + u * 64 + aRow) * Kl + col;
            GLL(src, dst + i * 8192);
        }
    };
    auto STAGE_B = [&](int buf, int u, int t) {
        char* dst = lds + (buf << 16) + 32768 + (u << 14) + tid * 16;
        long col = (long)t * 64 + colSw;
#pragma unroll
        for (int i = 0; i < 2; ++i) {
            const unsigned short* src = B + (n0 + (i * 2 + bWcLo) * 64 + u * 32 + bR) * Kl + col;
            GLL(src, dst + i * 8192);
        }
    };
    // 32x32x16 fragment reads. A: row = lane&31, k = (lane>>5)*8 + e.
    auto LDA = [&](int buf, int mp, int kabs) -> bf16x8 {
        int off = (((mp & 1) * 32 + l31) * 128 + kabs * 32 + l5 * 16) ^ ((l31 & 7) << 4);
        return *(const bf16x8*)(lds + (buf << 16) + ((mp >> 1) << 14) + (wr << 13) + off);
    };
    auto LDB = [&](int buf, int nh, int kabs) -> bf16x8 {
        int off = (l31 * 128 + kabs * 32 + l5 * 16) ^ ((l31 & 7) << 4);
        return *(const bf16x8*)(lds + (buf << 16) + 32768 + (nh << 14) + (wc << 12) + off);
    };

    f32x16 acc[4][2] = {};          // 128 regs (AGPR-eligible)
    bf16x8 afE[4][2], afO[4][2];    // 2 x 32 regs, ping-pong per phase
    bf16x8 bq[2][2];                // 16 regs, single set

    auto RD_AF = [&](bf16x8 (&d)[4][2], int buf, int h) {
#pragma unroll
        for (int mp = 0; mp < 4; ++mp)
#pragma unroll
            for (int kk = 0; kk < 2; ++kk)
                d[mp][kk] = LDA(buf, mp, h * 2 + kk);
    };
    auto RD_BQ = [&](int buf, int h) {
#pragma unroll
        for (int nh = 0; nh < 2; ++nh)
#pragma unroll
            for (int kk = 0; kk < 2; ++kk)
                bq[nh][kk] = LDB(buf, nh, h * 2 + kk);
    };
    auto MFMA16 = [&](bf16x8 (&af)[4][2]) {
        __builtin_amdgcn_s_setprio(1);
#pragma unroll
        for (int kk = 0; kk < 2; ++kk)
#pragma unroll
            for (int mp = 0; mp < 4; ++mp)
#pragma unroll
                for (int nh = 0; nh < 2; ++nh)
                    acc[mp][nh] = __builtin_amdgcn_mfma_f32_32x32x16_bf16(
                        af[mp][kk], bq[nh][kk], acc[mp][nh], 0, 0, 0);
        __builtin_amdgcn_s_setprio(0);
    };

    const int NT = K >> 6;

    // prologue: stage tiles 0 and 1 (16 GLL); tile0 visible, tile1 in flight
    STAGE_A(0, 0, 0); STAGE_A(0, 1, 0); STAGE_B(0, 0, 0); STAGE_B(0, 1, 0);
    STAGE_A(1, 0, 1); STAGE_A(1, 1, 1); STAGE_B(1, 0, 1); STAGE_B(1, 1, 1);
    WAITV(8);
    BARRIER();
    RD_AF(afE, 0, 0);   // af(t=0, kk01)

    for (int t = 0; t < NT; ++t) {
        const int c = t & 1, nx = c ^ 1;
        // ---- phase 0: MFMA kk01, prefetch af kk23 ----
        RD_BQ(c, 0);                       // 4 ds_read (this phase's B)
        BARRIER();
        RD_AF(afO, c, 1);                  // 8 ds_read (NEXT phase's A)
        WAITL(8);                          // drain afE + bq, leave afO in flight
        MFMA16(afE);
        BARRIER();
        // ---- phase 1: MFMA kk23, prefetch af(t+1) kk01, stage t+2 ----
        RD_BQ(c, 1);                       // 4 ds_read
        WAITV(0);                          // gate tile t+1 (staged a full tile ago)
        BARRIER();
        if (t + 1 < NT) {
            RD_AF(afE, nx, 0);             // 8 ds_read into buf t+1
            WAITL(8);                      // drain afO + bq, leave afE in flight
        } else {
            WAITL(0);
        }
        if (t + 2 < NT) {                  // stage tile t+2 into buf c (reads drained)
            STAGE_A(c, 0, t + 2); STAGE_A(c, 1, t + 2);
            STAGE_B(c, 0, t + 2); STAGE_B(c, 1, t + 2);
        }
        MFMA16(afO);
        BARRIER();
    }

    // epilogue: 32x32 D mapping col = lane&31, row = (reg&3) + 8*(reg>>2) + 4*(lane>>5)
#pragma unroll
    for (int nh = 0; nh < 2; ++nh) {
        const long col = n0 + wc * 64 + nh * 32 + l31;
        const float bv = bias[col];
#pragma unroll
        for (int mp = 0; mp < 4; ++mp) {
            const long rowb = m0 + wr * 128 + mp * 32 + 4 * l5;
            float* Cp = C + rowb * (long)N + col;
#pragma unroll
            for (int r = 0; r < 16; ++r) {
                const long row = (r & 3) + 8 * (r >> 2);
                Cp[row * (long)N] = acc[mp][nh][r] + bv;
            }
        }
    }
}

// fallback: m97-structure 128x128 (verified round 1) for non-conforming shapes
__global__ __launch_bounds__(256) void gemm_bt_bias(const unsigned short* __restrict__ A,
                                                    const unsigned short* __restrict__ B,
                                                    const float* __restrict__ bias,
                                                    float* __restrict__ C,
                                                    int M, int N, int K) {
    __shared__ unsigned short lds_a[128 * 32];
    __shared__ unsigned short lds_b[128 * 32];
    const int tid  = threadIdx.x;
    const int lane = tid & 63;
    const int wave = tid >> 6;
    const int wrr = wave >> 1, wcc = wave & 1;
    const int l15 = lane & 15, l4 = lane >> 4;
    const int nTilesN = N / 128;
    const long m0 = (long)(blockIdx.x / nTilesN) * 128;
    const long n0 = (long)(blockIdx.x % nTilesN) * 128;
    f32x4 acc[4][4] = {};
    const unsigned short* aSrc = A + (m0 + (tid >> 2)) * (long)K + ((tid & 3) * 8);
    const unsigned short* bSrc = B + (n0 + (tid >> 2)) * (long)K + ((tid & 3) * 8);
    char* aDst = (char*)lds_a + tid * 16;
    char* bDst = (char*)lds_b + tid * 16;
    for (int k0 = 0; k0 < K; k0 += 32) {
#pragma unroll
        for (int i = 0; i < 2; i++) {
            GLL(aSrc + (long)i * 64 * K + k0, aDst + i * 4096);
            GLL(bSrc + (long)i * 64 * K + k0, bDst + i * 4096);
        }
        __syncthreads();
        bf16x8 afr[4], bfr[4];
#pragma unroll
        for (int r = 0; r < 4; r++)
            afr[r] = *(const bf16x8*)&lds_a[(wrr * 64 + r * 16 + l15) * 32 + l4 * 8];
#pragma unroll
        for (int c = 0; c < 4; c++)
            bfr[c] = *(const bf16x8*)&lds_b[(wcc * 64 + c * 16 + l15) * 32 + l4 * 8];
#pragma unroll
        for (int r = 0; r < 4; r++)
#pragma unroll
            for (int c = 0; c < 4; c++)
                acc[r][c] = __builtin_amdgcn_mfma_f32_16x16x32_bf16(afr[r], bfr[c], acc[r][c], 0, 0, 0);
        __syncthreads();
    }
#pragma unroll
    for (int c = 0; c < 4; c++) {
        const long n = n0 + wcc * 64 + c * 16 + l15;
        const float bv = bias[n];
#pragma unroll
        for (int r = 0; r < 4; r++) {
            const long m = m0 + wrr * 64 + r * 16 + l4 * 4;
            float* Cp = C + m * (long)N + n;
#pragma unroll
            for (int j = 0; j < 4; j++)
                Cp[(long)j * N] = acc[r][c][j] + bv;
        }
    }
}

extern "C" void kernel_launch(void* const* d_in, const int* in_sizes, int n_in,
                              void* d_out, int out_size, void* d_ws, size_t ws_size,
                              hipStream_t stream) {
    const float* x    = (const float*)d_in[0];
    const float* w    = (const float*)d_in[1];
    const float* bias = (const float*)d_in[2];
    float* out = (float*)d_out;

    const long Nn = in_sizes[2];             // OUT = 4096
    const long Kk = (long)in_sizes[1] / Nn;  // IN  = 16384
    const long Mm = (long)in_sizes[0] / Kk;  // B*S = 8192

    unsigned short* aB = (unsigned short*)d_ws;
    unsigned short* bB = aB + Mm * Kk;
    cvt_f32_bf16<<<2048, 256, 0, stream>>>(x, aB, Mm * Kk);
    cvt_f32_bf16<<<2048, 256, 0, stream>>>(w, bB, Nn * Kk);

    if ((Mm & 255) == 0 && (Nn & 255) == 0 && (Kk & 63) == 0 && Kk >= 256) {
        const int grid = (int)((Mm >> 8) * (Nn >> 8));
        gemm256_32x32<<<grid, 512, 0, stream>>>(aB, bB, bias, out, (int)Mm, (int)Nn, (int)Kk);
    } else {
        const int grid = (int)((Mm / 128) * (Nn / 128));
        gemm_bt_bias<<<grid, 256, 0, stream>>>(aB, bB, bias, out, (int)Mm, (int)Nn, (int)Kk);
    }
}